// Round 3
// baseline (185.073 us; speedup 1.0000x reference)
//
#include <hip/hip_runtime.h>
#include <hip/hip_fp16.h>

#define F_IN 48
#define F_HID 64
#define GSH 7            // nodes per bucket = 128
#define GSZ 128
#define MAXB 1024        // supports N <= 131072 (pack: src in 17 bits, g in 7)
#define CAPSH 12         // ebuf: edges capacity per bucket = 4096
#define CAP 4096
#define CAPE (CAP - GSZ) // edge clamp so padded slot lists fit in SCAP
#define SSH 13           // srcSorted: padded slots per bucket = 8192
#define SCAP 8192
#define CHUNK 4096       // edges per passA block (16 per thread)
#define FIXS 24          // fixed slots processed per node (pad floor)

__device__ __forceinline__ bool detect64(const int* __restrict__ e) {
    return ((e[1] | e[3] | e[5] | e[7]) == 0);
}
__device__ __forceinline__ int load_src(const int* e, int i, int E, bool is64) {
    return e[is64 ? (long)2 * i : (long)i];
}
__device__ __forceinline__ int load_dst(const int* e, int i, int E, bool is64) {
    return e[is64 ? (long)2 * (E + i) : (long)(E + i)];
}
__device__ __forceinline__ float rdlane(float v, int l) {
    return __uint_as_float(__builtin_amdgcn_readlane(__float_as_uint(v), l));
}
// acc_lo += f32(lo16(h)); acc_hi += f32(hi16(h)) -- one VALU op each, exact.
__device__ __forceinline__ void fmix2(float& alo, float& ahi, unsigned h) {
    asm("v_fma_mix_f32 %0, %2, 1.0, %0 op_sel_hi:[1,0,0]\n\t"
        "v_fma_mix_f32 %1, %2, 1.0, %1 op_sel:[1,0,0] op_sel_hi:[1,0,0]"
        : "+v"(alo), "+v"(ahi) : "v"(h));
}

// ---- pass A: chunk reservation (unchanged) ----
__global__ __launch_bounds__(256) void passA(const int* __restrict__ e,
                                             int* __restrict__ bcnt,
                                             int* __restrict__ ebuf, int E, int B) {
    __shared__ int lcnt[MAXB], lbase[MAXB];
    bool is64 = detect64(e);
    bool vec = ((E & 3) == 0);
    int base = blockIdx.x * CHUNK;
    for (int t = threadIdx.x; t < B; t += 256) lcnt[t] = 0;
    __syncthreads();
    int pk[16], bk[16], rk[16];
#pragma unroll
    for (int g = 0; g < 4; ++g) {
        int i = base + (((g << 8) + (int)threadIdx.x) << 2);
        int r = g * 4;
        if (vec && i + 3 < E) {
            int4 s4, d4;
            if (is64) {
                const int4* p = (const int4*)(e + (size_t)2 * i);
                int4 a = p[0], bb = p[1];
                s4 = make_int4(a.x, a.z, bb.x, bb.z);
                const int4* q = (const int4*)(e + (size_t)2 * E + (size_t)2 * i);
                int4 c = q[0], dd = q[1];
                d4 = make_int4(c.x, c.z, dd.x, dd.z);
            } else {
                s4 = *(const int4*)(e + i);
                d4 = *(const int4*)(e + E + i);
            }
            int ss[4] = {s4.x, s4.y, s4.z, s4.w};
            int dv[4] = {d4.x, d4.y, d4.z, d4.w};
#pragma unroll
            for (int u = 0; u < 4; ++u) {
                pk[r + u] = ss[u] | ((dv[u] & (GSZ - 1)) << 17);
                bk[r + u] = dv[u] >> GSH;
                rk[r + u] = atomicAdd(&lcnt[bk[r + u]], 1);
            }
        } else {
#pragma unroll
            for (int u = 0; u < 4; ++u) {
                int ii = i + u;
                if (ii < E) {
                    int s = load_src(e, ii, E, is64);
                    int d = load_dst(e, ii, E, is64);
                    pk[r + u] = s | ((d & (GSZ - 1)) << 17);
                    bk[r + u] = d >> GSH;
                    rk[r + u] = atomicAdd(&lcnt[bk[r + u]], 1);
                } else {
                    bk[r + u] = -1;
                }
            }
        }
    }
    __syncthreads();
    for (int t = threadIdx.x; t < B; t += 256) {
        int c = lcnt[t];
        lbase[t] = c ? atomicAdd(&bcnt[t], c) : 0;
    }
    __syncthreads();
#pragma unroll
    for (int r = 0; r < 16; ++r) {
        if (bk[r] >= 0) {
            int pos = lbase[bk[r]] + rk[r];
            if (pos < CAPE) ebuf[((size_t)bk[r] << CAPSH) + pos] = pk[r];
        }
    }
}

// ---- pass B: bucket sort -> PADDED slot lists: [edges..., self, N-pads...]
// each node's list padded to pl = even(max(deg+1, 24)); scan over pl. ----
__global__ __launch_bounds__(256) void passB(const int* __restrict__ ebuf,
                                             const int* __restrict__ bcnt,
                                             const float* __restrict__ x,
                                             int* __restrict__ rowStart,
                                             int* __restrict__ deg,
                                             float* __restrict__ dinv,
                                             int* __restrict__ srcSorted,
                                             __half* __restrict__ y, int N) {
    __shared__ int cnt[GSZ], inc[GSZ], exo[GSZ];
    __shared__ float ldinv[GSZ];
    int b = blockIdx.x, t = threadIdx.x;
    int m = min(bcnt[b], CAPE);
    const int* eb = ebuf + ((size_t)b << CAPSH);
    if (t < GSZ) cnt[t] = 0;
    __syncthreads();
    int gk[16], sk[16], rk[16];
    int iters = (m + 255) >> 8;   // <= 16
    for (int it = 0; it < iters; ++it) {
        int i = t + (it << 8);
        if (i < m) {
            int pkv = eb[i];
            gk[it] = pkv >> 17;
            sk[it] = pkv & 0x1FFFF;
            rk[it] = atomicAdd(&cnt[gk[it]], 1);
        } else {
            gk[it] = -1;
        }
    }
    __syncthreads();
    int myc = (t < GSZ) ? cnt[t] : 0;
    int pl = (max(myc + 1, FIXS) + 1) & ~1;   // even, >= FIXS, >= deg+1
    if (t < GSZ) inc[t] = pl;
    __syncthreads();
    for (int o = 1; o < GSZ; o <<= 1) {
        int v = (t < GSZ && t >= o) ? inc[t - o] : 0;
        __syncthreads();
        if (t < GSZ) inc[t] += v;
        __syncthreads();
    }
    if (t < GSZ) {
        int ex = inc[t] - pl;
        exo[t] = ex;
        float di = rsqrtf((float)myc + 1.0f);
        ldinv[t] = di;
        int node = (b << GSH) + t;
        if (node < N) {
            rowStart[node] = (b << SSH) + ex;
            deg[node] = myc;
            dinv[node] = di;
        }
        // self at slot deg, zero-row pads after (written for pad nodes too;
        // regions disjoint by scan)
        int* sb = srcSorted + ((size_t)b << SSH) + ex;
        sb[myc] = node;
        for (int j = myc + 1; j < pl; ++j) sb[j] = N;
    }
    __syncthreads();
    int s0b = b << SSH;
    for (int it = 0; it < iters; ++it) {
        if (gk[it] >= 0)
            srcSorted[s0b + exo[gk[it]] + rk[it]] = sk[it];
    }
    // y16[n][k] = half(dinv[n]*x[n][k]), rows padded to 64; 4 halves/thread-step
    int nodeBase = b << GSH;
    for (int q = t; q < GSZ * 16; q += 256) {
        int nl = q >> 4, k4 = (q & 15) << 2;
        int node = nodeBase + nl;
        if (node < N) {
            ushort4 hv;
            if (k4 < F_IN) {
                float di = ldinv[nl];
                float4 xv = *(const float4*)(x + (size_t)node * F_IN + k4);
                hv.x = __half_as_ushort(__float2half(di * xv.x));
                hv.y = __half_as_ushort(__float2half(di * xv.y));
                hv.z = __half_as_ushort(__float2half(di * xv.z));
                hv.w = __half_as_ushort(__float2half(di * xv.w));
            } else {
                hv.x = hv.y = hv.z = hv.w = 0;
            }
            *(ushort4*)((char*)y + ((size_t)node << 7) + ((size_t)k4 << 1)) = hv;
        }
    }
}

// ---- fused: 4 nodes/wave. Slot indices via SCALAR loads (s_load, uniform),
// row base on SALU -> gathers are saddr + constant VGPR offset: zero VALU,
// zero DS on the address path. Full wave covers one 128B row per load. ----
__global__ __launch_bounds__(256) void fused1(const __half* __restrict__ y,
                                              const float* __restrict__ W1,
                                              const float* __restrict__ b1,
                                              const float* __restrict__ W2,
                                              const float* __restrict__ dinv,
                                              const int* __restrict__ rowStart,
                                              const int* __restrict__ deg,
                                              const int* __restrict__ srcSorted,
                                              float* __restrict__ g2, int N) {
    const int lane = threadIdx.x & 63;
    const int warp = __builtin_amdgcn_readfirstlane(threadIdx.x >> 6);
    const int base = blockIdx.x * 16 + warp * 4;
    const char* yb = (const char*)y;
    const unsigned fb = (unsigned)(lane & 31) << 2;   // dword offset in row

    int n0 = base, n1 = base + 1, n2 = base + 2, n3 = base + 3;
    int dd0 = (n0 < N) ? __builtin_amdgcn_readfirstlane(deg[n0]) + 1 : 0;
    int dd1 = (n1 < N) ? __builtin_amdgcn_readfirstlane(deg[n1]) + 1 : 0;
    int dd2 = (n2 < N) ? __builtin_amdgcn_readfirstlane(deg[n2]) + 1 : 0;
    int dd3 = (n3 < N) ? __builtin_amdgcn_readfirstlane(deg[n3]) + 1 : 0;
    int rs0 = (n0 < N) ? __builtin_amdgcn_readfirstlane(rowStart[n0]) : 0;
    int rs1 = (n1 < N) ? __builtin_amdgcn_readfirstlane(rowStart[n1]) : 0;
    int rs2 = (n2 < N) ? __builtin_amdgcn_readfirstlane(rowStart[n2]) : 0;
    int rs3 = (n3 < N) ? __builtin_amdgcn_readfirstlane(rowStart[n3]) : 0;
    const int* sp0 = srcSorted + rs0;
    const int* sp1 = srcSorted + rs1;
    const int* sp2 = srcSorted + rs2;
    const int* sp3 = srcSorted + rs3;

    float ax0 = 0, ay0 = 0, ax1 = 0, ay1 = 0;
    float ax2 = 0, ay2 = 0, ax3 = 0, ay3 = 0;

    // fixed region: slots [0, 24) are always valid (padding guarantees)
#pragma unroll
    for (int s = 0; s < FIXS; ++s) {
        unsigned i0 = (unsigned)__builtin_amdgcn_readfirstlane(sp0[s]);
        unsigned i1 = (unsigned)__builtin_amdgcn_readfirstlane(sp1[s]);
        unsigned i2 = (unsigned)__builtin_amdgcn_readfirstlane(sp2[s]);
        unsigned i3 = (unsigned)__builtin_amdgcn_readfirstlane(sp3[s]);
        unsigned v0 = *(const unsigned*)(yb + (((size_t)i0) << 7) + fb);
        unsigned v1 = *(const unsigned*)(yb + (((size_t)i1) << 7) + fb);
        unsigned v2 = *(const unsigned*)(yb + (((size_t)i2) << 7) + fb);
        unsigned v3 = *(const unsigned*)(yb + (((size_t)i3) << 7) + fb);
        fmix2(ax0, ay0, v0);
        fmix2(ax1, ay1, v1);
        fmix2(ax2, ay2, v2);
        fmix2(ax3, ay3, v3);
    }
    // dynamic region (deg >= 24, uncommon); uniform control, scalar selects
    int maxD = max(max(dd0, dd1), max(dd2, dd3));
    for (int s = FIXS; s < maxD; ++s) {
        unsigned i0 = (unsigned)((s < dd0) ? __builtin_amdgcn_readfirstlane(sp0[s]) : N);
        unsigned i1 = (unsigned)((s < dd1) ? __builtin_amdgcn_readfirstlane(sp1[s]) : N);
        unsigned i2 = (unsigned)((s < dd2) ? __builtin_amdgcn_readfirstlane(sp2[s]) : N);
        unsigned i3 = (unsigned)((s < dd3) ? __builtin_amdgcn_readfirstlane(sp3[s]) : N);
        unsigned v0 = *(const unsigned*)(yb + (((size_t)i0) << 7) + fb);
        unsigned v1 = *(const unsigned*)(yb + (((size_t)i1) << 7) + fb);
        unsigned v2 = *(const unsigned*)(yb + (((size_t)i2) << 7) + fb);
        unsigned v3 = *(const unsigned*)(yb + (((size_t)i3) << 7) + fb);
        fmix2(ax0, ay0, v0);
        fmix2(ax1, ay1, v1);
        fmix2(ax2, ay2, v2);
        fmix2(ax3, ay3, v3);
    }

    // every lane now holds a[2*(lane&31)] in ax, a[2*(lane&31)+1] in ay
    float di0 = (n0 < N) ? dinv[n0] : 0.0f;
    float di1 = (n1 < N) ? dinv[n1] : 0.0f;
    float di2 = (n2 < N) ? dinv[n2] : 0.0f;
    float di3 = (n3 < N) ? dinv[n3] : 0.0f;
    ax0 *= di0; ay0 *= di0; ax1 *= di1; ay1 *= di1;
    ax2 *= di2; ay2 *= di2; ax3 *= di3; ay3 *= di3;

    // GEMM epilogue: readlane broadcast (proven round-0 form)
    float h0 = b1[lane], h1 = h0, h2 = h0, h3 = h0;
#pragma unroll
    for (int k = 0; k < F_IN; k += 2) {
        float wA = W1[k * F_HID + lane];
        float wB = W1[(k + 1) * F_HID + lane];
        const int q = k >> 1;
        h0 = fmaf(rdlane(ax0, q), wA, h0); h0 = fmaf(rdlane(ay0, q), wB, h0);
        h1 = fmaf(rdlane(ax1, q), wA, h1); h1 = fmaf(rdlane(ay1, q), wB, h1);
        h2 = fmaf(rdlane(ax2, q), wA, h2); h2 = fmaf(rdlane(ay2, q), wB, h2);
        h3 = fmaf(rdlane(ax3, q), wA, h3); h3 = fmaf(rdlane(ay3, q), wB, h3);
    }
    h0 = fmaxf(h0, 0.0f); h1 = fmaxf(h1, 0.0f);
    h2 = fmaxf(h2, 0.0f); h3 = fmaxf(h3, 0.0f);

    float2 w2 = ((const float2*)W2)[lane];
    float t00 = h0 * w2.x, t01 = h0 * w2.y;
    float t10 = h1 * w2.x, t11 = h1 * w2.y;
    float t20 = h2 * w2.x, t21 = h2 * w2.y;
    float t30 = h3 * w2.x, t31 = h3 * w2.y;
#pragma unroll
    for (int off = 32; off > 0; off >>= 1) {
        t00 += __shfl_down(t00, off, 64); t01 += __shfl_down(t01, off, 64);
        t10 += __shfl_down(t10, off, 64); t11 += __shfl_down(t11, off, 64);
        t20 += __shfl_down(t20, off, 64); t21 += __shfl_down(t21, off, 64);
        t30 += __shfl_down(t30, off, 64); t31 += __shfl_down(t31, off, 64);
    }
    if (lane == 0) {
        float2* g2v = (float2*)g2;
        if (n0 < N) g2v[n0] = make_float2(di0 * t00, di0 * t01);
        if (n1 < N) g2v[n1] = make_float2(di1 * t10, di1 * t11);
        if (n2 < N) g2v[n2] = make_float2(di2 * t20, di2 * t21);
        if (n3 < N) g2v[n3] = make_float2(di3 * t30, di3 * t31);
    }
}

// ---- layer-2 aggregation: 16 lanes per node; self is in the slot list ----
__global__ __launch_bounds__(256) void agg2(const int* __restrict__ rowStart,
                                            const int* __restrict__ deg,
                                            const int* __restrict__ srcSorted,
                                            const float* __restrict__ g2,
                                            const float* __restrict__ dinv,
                                            const float* __restrict__ b2,
                                            float* __restrict__ out, int N) {
    int gid = blockIdx.x * 256 + threadIdx.x;
    int node = gid >> 4, l16 = gid & 15;
    if (node >= N) return;
    const char* gb = (const char*)g2;
    int rs = rowStart[node], dd = deg[node] + 1;
    float a0 = 0.0f, a1 = 0.0f;
    for (int j = l16; j < dd; j += 16) {
        unsigned o = (unsigned)srcSorted[rs + j] << 3;
        float2 v = *(const float2*)(gb + o);
        a0 += v.x;
        a1 += v.y;
    }
#pragma unroll
    for (int m = 1; m < 16; m <<= 1) {
        a0 += __shfl_xor(a0, m, 64);
        a1 += __shfl_xor(a1, m, 64);
    }
    if (l16 == 0) {
        float di = dinv[node];
        out[2 * node + 0] = di * a0 + b2[0];
        out[2 * node + 1] = di * a1 + b2[1];
    }
}

extern "C" void kernel_launch(void* const* d_in, const int* in_sizes, int n_in,
                              void* d_out, int out_size, void* d_ws, size_t ws_size,
                              hipStream_t stream) {
    const float* x  = (const float*)d_in[0];
    const int* eidx = (const int*)d_in[1];
    const float* W1 = (const float*)d_in[2];
    const float* b1 = (const float*)d_in[3];
    const float* W2 = (const float*)d_in[4];
    const float* b2 = (const float*)d_in[5];
    float* out = (float*)d_out;

    int N = in_sizes[0] / F_IN;   // 100000
    int E = in_sizes[1] / 2;      // 1600000
    int B = (N + GSZ - 1) >> GSH; // 782 buckets (<= MAXB)

    // layout: y16 rows 0..N (row N = zero row), then bcnt — adjacent so one
    // memset clears both (row N is 128 B; bcnt is MAXB*4 B).
    char* ws = (char*)d_ws;
    __half* y16       = (__half*)ws;   ws += (size_t)(N + 1) * 64 * 2;
    int*    bcnt      = (int*)ws;      ws += MAXB * 4;
    int*    deg       = (int*)ws;      ws += (size_t)N * 4;
    int*    rowStart  = (int*)ws;      ws += (size_t)N * 4;
    float*  dinv      = (float*)ws;    ws += (size_t)N * 4;
    float*  g2        = (float*)ws;    ws += (size_t)N * 2 * 4;
    ws = (char*)(((size_t)ws + 255) & ~(size_t)255);
    int*    ebuf      = (int*)ws;      ws += (size_t)MAXB * CAP * 4;
    int*    srcSorted = (int*)ws;      ws += (size_t)MAXB * SCAP * 4;

    hipMemsetAsync(y16 + (size_t)N * 64, 0, 128 + MAXB * 4, stream);

    passA<<<(E + CHUNK - 1) / CHUNK, 256, 0, stream>>>(eidx, bcnt, ebuf, E, B);
    passB<<<B, 256, 0, stream>>>(ebuf, bcnt, x, rowStart, deg, dinv, srcSorted,
                                 y16, N);
    fused1<<<(N + 15) / 16, 256, 0, stream>>>(y16, W1, b1, W2, dinv, rowStart, deg,
                                              srcSorted, g2, N);
    agg2<<<(N * 16 + 255) / 256, 256, 0, stream>>>(rowStart, deg, srcSorted, g2,
                                                   dinv, b2, out, N);
}

// Round 4
// 180.733 us; speedup vs baseline: 1.0240x; 1.0240x over previous
//
#include <hip/hip_runtime.h>
#include <hip/hip_fp16.h>

#define F_IN 48
#define F_HID 64
#define GSH 7            // nodes per bucket = 128
#define GSZ 128
#define MAXB 1024        // supports N <= 131072 (pack: src in 17 bits, g in 7)
#define CAPSH 12         // edges capacity per bucket = 4096 (avg 2048, +45 sigma)
#define CAP 4096
#define CHUNK 4096       // edges per passA block (16 per thread)

__device__ __forceinline__ bool detect64(const int* __restrict__ e) {
    return ((e[1] | e[3] | e[5] | e[7]) == 0);
}
__device__ __forceinline__ int load_src(const int* e, int i, int E, bool is64) {
    return e[is64 ? (long)2 * i : (long)i];
}
__device__ __forceinline__ int load_dst(const int* e, int i, int E, bool is64) {
    return e[is64 ? (long)2 * (E + i) : (long)(E + i)];
}
__device__ __forceinline__ float rdlane(float v, int l) {
    return __uint_as_float(__builtin_amdgcn_readlane(__float_as_uint(v), l));
}
// acc_lo += f32(lo16(h)); acc_hi += f32(hi16(h)) -- one VALU op each,
// bitwise identical to v_cvt_f32_f16 + v_add_f32 (x*1.0 exact).
__device__ __forceinline__ void fmix2(float& alo, float& ahi, unsigned h) {
    asm("v_fma_mix_f32 %0, %2, 1.0, %0 op_sel_hi:[1,0,0]\n\t"
        "v_fma_mix_f32 %1, %2, 1.0, %1 op_sel:[1,0,0] op_sel_hi:[1,0,0]"
        : "+v"(alo), "+v"(ahi) : "v"(h));
}

// ---- pass A: chunk reservation. First-pass LDS atomicAdd RETURNS each edge's
// within-block rank -> no second LDS-atomic pass needed. int4 edge loads. ----
__global__ __launch_bounds__(256) void passA(const int* __restrict__ e,
                                             int* __restrict__ bcnt,
                                             int* __restrict__ ebuf, int E, int B) {
    __shared__ int lcnt[MAXB], lbase[MAXB];
    bool is64 = detect64(e);
    bool vec = ((E & 3) == 0);
    int base = blockIdx.x * CHUNK;
    for (int t = threadIdx.x; t < B; t += 256) lcnt[t] = 0;
    __syncthreads();
    int pk[16], bk[16], rk[16];
#pragma unroll
    for (int g = 0; g < 4; ++g) {
        int i = base + (((g << 8) + (int)threadIdx.x) << 2);
        int r = g * 4;
        if (vec && i + 3 < E) {
            int4 s4, d4;
            if (is64) {
                const int4* p = (const int4*)(e + (size_t)2 * i);
                int4 a = p[0], bb = p[1];
                s4 = make_int4(a.x, a.z, bb.x, bb.z);
                const int4* q = (const int4*)(e + (size_t)2 * E + (size_t)2 * i);
                int4 c = q[0], dd = q[1];
                d4 = make_int4(c.x, c.z, dd.x, dd.z);
            } else {
                s4 = *(const int4*)(e + i);
                d4 = *(const int4*)(e + E + i);
            }
            int ss[4] = {s4.x, s4.y, s4.z, s4.w};
            int dv[4] = {d4.x, d4.y, d4.z, d4.w};
#pragma unroll
            for (int u = 0; u < 4; ++u) {
                pk[r + u] = ss[u] | ((dv[u] & (GSZ - 1)) << 17);
                bk[r + u] = dv[u] >> GSH;
                rk[r + u] = atomicAdd(&lcnt[bk[r + u]], 1);
            }
        } else {
#pragma unroll
            for (int u = 0; u < 4; ++u) {
                int ii = i + u;
                if (ii < E) {
                    int s = load_src(e, ii, E, is64);
                    int d = load_dst(e, ii, E, is64);
                    pk[r + u] = s | ((d & (GSZ - 1)) << 17);
                    bk[r + u] = d >> GSH;
                    rk[r + u] = atomicAdd(&lcnt[bk[r + u]], 1);
                } else {
                    bk[r + u] = -1;
                }
            }
        }
    }
    __syncthreads();
    for (int t = threadIdx.x; t < B; t += 256) {
        int c = lcnt[t];
        lbase[t] = c ? atomicAdd(&bcnt[t], c) : 0;
    }
    __syncthreads();
#pragma unroll
    for (int r = 0; r < 16; ++r) {
        if (bk[r] >= 0) {
            int pos = lbase[bk[r]] + rk[r];
            if (pos < CAP) ebuf[((size_t)bk[r] << CAPSH) + pos] = pk[r];
        }
    }
}

// ---- pass B: per-bucket sort with rank capture -> deg/rowStart/dinv/srcSorted
// + vectorized y16 prep ----
__global__ __launch_bounds__(256) void passB(const int* __restrict__ ebuf,
                                             const int* __restrict__ bcnt,
                                             const float* __restrict__ x,
                                             int* __restrict__ rowStart,
                                             int* __restrict__ deg,
                                             float* __restrict__ dinv,
                                             int* __restrict__ srcSorted,
                                             __half* __restrict__ y, int N) {
    __shared__ int cnt[GSZ], inc[GSZ], exo[GSZ];
    __shared__ float ldinv[GSZ];
    int b = blockIdx.x, t = threadIdx.x;
    int m = min(bcnt[b], CAP);
    const int* eb = ebuf + ((size_t)b << CAPSH);
    if (t < GSZ) cnt[t] = 0;
    __syncthreads();
    int gk[16], sk[16], rk[16];
    int iters = (m + 255) >> 8;   // <= 16
    for (int it = 0; it < iters; ++it) {
        int i = t + (it << 8);
        if (i < m) {
            int pkv = eb[i];
            gk[it] = pkv >> 17;
            sk[it] = pkv & 0x1FFFF;
            rk[it] = atomicAdd(&cnt[gk[it]], 1);
        } else {
            gk[it] = -1;
        }
    }
    __syncthreads();
    int myc = (t < GSZ) ? cnt[t] : 0;
    if (t < GSZ) inc[t] = myc;
    __syncthreads();
    for (int o = 1; o < GSZ; o <<= 1) {
        int v = (t < GSZ && t >= o) ? inc[t - o] : 0;
        __syncthreads();
        if (t < GSZ) inc[t] += v;
        __syncthreads();
    }
    if (t < GSZ) {
        int ex = inc[t] - myc;
        exo[t] = ex;
        float di = rsqrtf((float)myc + 1.0f);
        ldinv[t] = di;
        int node = (b << GSH) + t;
        if (node < N) {
            rowStart[node] = (b << CAPSH) + ex;
            deg[node] = myc;
            dinv[node] = di;
        }
    }
    __syncthreads();
    int s0b = b << CAPSH;
    for (int it = 0; it < iters; ++it) {
        if (gk[it] >= 0)
            srcSorted[s0b + exo[gk[it]] + rk[it]] = sk[it];
    }
    // y16[n][k] = half(dinv[n]*x[n][k]), rows padded to 64; 4 halves/thread-step
    int nodeBase = b << GSH;
    for (int q = t; q < GSZ * 16; q += 256) {
        int nl = q >> 4, k4 = (q & 15) << 2;
        int node = nodeBase + nl;
        if (node < N) {
            ushort4 hv;
            if (k4 < F_IN) {
                float di = ldinv[nl];
                float4 xv = *(const float4*)(x + (size_t)node * F_IN + k4);
                hv.x = __half_as_ushort(__float2half(di * xv.x));
                hv.y = __half_as_ushort(__float2half(di * xv.y));
                hv.z = __half_as_ushort(__float2half(di * xv.z));
                hv.w = __half_as_ushort(__float2half(di * xv.w));
            } else {
                hv.x = hv.y = hv.z = hv.w = 0;
            }
            *(ushort4*)((char*)y + ((size_t)node << 7) + ((size_t)k4 << 1)) = hv;
        }
    }
}

// ---- fused: 8 nodes/wave (2x MLP vs round-0), 96 gathers in flight,
// bpermute idx broadcast, fmix accumulate, readlane GEMM epilogue ----
__global__ __launch_bounds__(256) void fused1(const __half* __restrict__ y,
                                              const float* __restrict__ W1,
                                              const float* __restrict__ b1,
                                              const float* __restrict__ W2,
                                              const float* __restrict__ dinv,
                                              const int* __restrict__ rowStart,
                                              const int* __restrict__ deg,
                                              const int* __restrict__ srcSorted,
                                              float* __restrict__ g2, int N) {
    const int lane = threadIdx.x & 63;
    const int sub = lane >> 5;
    const int fl = lane & 31;
    const int base = blockIdx.x * 32 + (threadIdx.x >> 6) * 8;
    const char* yb = (const char*)y;
    const unsigned fb = (unsigned)fl << 2;

    int dn[8], rs[8], idx[8];
    float ax[8], ay[8];
#pragma unroll
    for (int j = 0; j < 8; ++j) {
        int nj = base + j;
        dn[j] = (nj < N) ? deg[nj] : -1;
        rs[j] = (nj < N) ? rowStart[nj] : 0;
        // slot map per lane: [0,dn)=edges, dn=self, rest=zero row N
        idx[j] = N;
        if (lane < dn[j]) idx[j] = srcSorted[rs[j] + lane];
        else if (lane == dn[j]) idx[j] = base + j;
        ax[j] = 0.0f; ay[j] = 0.0f;
    }

    auto step = [&](int p) {
        int sA = 2 * p + sub;
        unsigned o[8], v[8];
#pragma unroll
        for (int j = 0; j < 8; ++j)
            o[j] = ((unsigned)__shfl(idx[j], sA, 64) << 7) + fb;
#pragma unroll
        for (int j = 0; j < 8; ++j)
            v[j] = *(const unsigned*)(yb + o[j]);
#pragma unroll
        for (int j = 0; j < 8; ++j)
            fmix2(ax[j], ay[j], v[j]);
    };
#pragma unroll
    for (int p = 0; p < 12; ++p) step(p);   // 96 independent gathers in flight
    int maxD = dn[0];
#pragma unroll
    for (int j = 1; j < 8; ++j) maxD = max(maxD, dn[j]);
    int maxSlot = maxD + 1;
    for (int p = 12; p < 32 && 2 * p < maxSlot; ++p) step(p);  // uncommon
    if (maxSlot > 64) {  // astronomically rare
        const __half2* yp = (const __half2*)y;
        for (int s = 64; s < maxSlot; ++s) {
            if (sub == 0) {
#pragma unroll
                for (int j = 0; j < 8; ++j) {
                    if (s <= dn[j]) {
                        int src = (s < dn[j]) ? srcSorted[rs[j] + s] : (base + j);
                        float2 f = __half22float2(yp[((long)src << 5) + fl]);
                        ax[j] += f.x; ay[j] += f.y;
                    }
                }
            }
        }
    }

    // combine half-waves: lanes then hold a[2*fl], a[2*fl+1]; scale by dinv
    float di[8];
#pragma unroll
    for (int j = 0; j < 8; ++j) {
        ax[j] += __shfl(ax[j], lane ^ 32, 64);
        ay[j] += __shfl(ay[j], lane ^ 32, 64);
        int nj = base + j;
        di[j] = (nj < N) ? dinv[nj] : 0.0f;
        ax[j] *= di[j]; ay[j] *= di[j];
    }

    // GEMM epilogue: readlane broadcast (proven round-0 form)
    float bv = b1[lane];
    float h[8];
#pragma unroll
    for (int j = 0; j < 8; ++j) h[j] = bv;
#pragma unroll
    for (int k = 0; k < F_IN; k += 2) {
        float wA = W1[k * F_HID + lane];
        float wB = W1[(k + 1) * F_HID + lane];
        const int q = k >> 1;
#pragma unroll
        for (int j = 0; j < 8; ++j) {
            h[j] = fmaf(rdlane(ax[j], q), wA, h[j]);
            h[j] = fmaf(rdlane(ay[j], q), wB, h[j]);
        }
    }

    float2 w2 = ((const float2*)W2)[lane];
    float t0[8], t1[8];
#pragma unroll
    for (int j = 0; j < 8; ++j) {
        float hr = fmaxf(h[j], 0.0f);
        t0[j] = hr * w2.x; t1[j] = hr * w2.y;
    }
#pragma unroll
    for (int off = 32; off > 0; off >>= 1) {
#pragma unroll
        for (int j = 0; j < 8; ++j) {
            t0[j] += __shfl_down(t0[j], off, 64);
            t1[j] += __shfl_down(t1[j], off, 64);
        }
    }
    if (lane == 0) {
        float2* g2v = (float2*)g2;
#pragma unroll
        for (int j = 0; j < 8; ++j)
            if (base + j < N)
                g2v[base + j] = make_float2(di[j] * t0[j], di[j] * t1[j]);
    }
}

// ---- layer-2 aggregation: 16 lanes per node, 32-bit offsets ----
__global__ __launch_bounds__(256) void agg2(const int* __restrict__ rowStart,
                                            const int* __restrict__ deg,
                                            const int* __restrict__ srcSorted,
                                            const float* __restrict__ g2,
                                            const float* __restrict__ dinv,
                                            const float* __restrict__ b2,
                                            float* __restrict__ out, int N) {
    int gid = blockIdx.x * 256 + threadIdx.x;
    int node = gid >> 4, l16 = gid & 15;
    if (node >= N) return;
    const char* gb = (const char*)g2;
    int rs = rowStart[node], dn = deg[node];
    float a0 = 0.0f, a1 = 0.0f;
    for (int j = l16; j < dn; j += 16) {
        unsigned o = (unsigned)srcSorted[rs + j] << 3;
        float2 v = *(const float2*)(gb + o);
        a0 += v.x;
        a1 += v.y;
    }
#pragma unroll
    for (int m = 1; m < 16; m <<= 1) {
        a0 += __shfl_xor(a0, m, 64);
        a1 += __shfl_xor(a1, m, 64);
    }
    if (l16 == 0) {
        float2 self = *(const float2*)(gb + ((unsigned)node << 3));
        float di = dinv[node];
        out[2 * node + 0] = di * (a0 + self.x) + b2[0];
        out[2 * node + 1] = di * (a1 + self.y) + b2[1];
    }
}

extern "C" void kernel_launch(void* const* d_in, const int* in_sizes, int n_in,
                              void* d_out, int out_size, void* d_ws, size_t ws_size,
                              hipStream_t stream) {
    const float* x  = (const float*)d_in[0];
    const int* eidx = (const int*)d_in[1];
    const float* W1 = (const float*)d_in[2];
    const float* b1 = (const float*)d_in[3];
    const float* W2 = (const float*)d_in[4];
    const float* b2 = (const float*)d_in[5];
    float* out = (float*)d_out;

    int N = in_sizes[0] / F_IN;   // 100000
    int E = in_sizes[1] / 2;      // 1600000
    int B = (N + GSZ - 1) >> GSH; // 782 buckets (<= MAXB)

    // layout: y16 rows 0..N (row N = zero row), then bcnt — adjacent so one
    // memset clears both (row N is 128 B; bcnt is MAXB*4 B).
    char* ws = (char*)d_ws;
    __half* y16       = (__half*)ws;   ws += (size_t)(N + 1) * 64 * 2;
    int*    bcnt      = (int*)ws;      ws += MAXB * 4;
    int*    deg       = (int*)ws;      ws += (size_t)N * 4;
    int*    rowStart  = (int*)ws;      ws += (size_t)N * 4;
    float*  dinv      = (float*)ws;    ws += (size_t)N * 4;
    float*  g2        = (float*)ws;    ws += (size_t)N * 2 * 4;
    ws = (char*)(((size_t)ws + 255) & ~(size_t)255);
    int*    ebuf      = (int*)ws;      ws += (size_t)MAXB * CAP * 4;
    int*    srcSorted = (int*)ws;      ws += (size_t)MAXB * CAP * 4;

    hipMemsetAsync(y16 + (size_t)N * 64, 0, 128 + MAXB * 4, stream);

    passA<<<(E + CHUNK - 1) / CHUNK, 256, 0, stream>>>(eidx, bcnt, ebuf, E, B);
    passB<<<B, 256, 0, stream>>>(ebuf, bcnt, x, rowStart, deg, dinv, srcSorted,
                                 y16, N);
    fused1<<<(N + 31) / 32, 256, 0, stream>>>(y16, W1, b1, W2, dinv, rowStart, deg,
                                              srcSorted, g2, N);
    agg2<<<(N * 16 + 255) / 256, 256, 0, stream>>>(rowStart, deg, srcSorted, g2,
                                                   dinv, b2, out, N);
}

// Round 5
// 178.511 us; speedup vs baseline: 1.0368x; 1.0124x over previous
//
#include <hip/hip_runtime.h>
#include <hip/hip_fp16.h>

#define F_IN 48
#define F_HID 64
#define GSH 7            // nodes per bucket = 128
#define GSZ 128
#define MAXB 1024        // supports N <= 131072 (pack: src in 17 bits, g in 7)
#define CAPSH 12         // edges capacity per bucket = 4096 (avg 2048, +45 sigma)
#define CAP 4096
#define CHUNK 4096       // edges per passA block (16 per thread)
#define NPW 16           // nodes per wave in gemm1

__device__ __forceinline__ bool detect64(const int* __restrict__ e) {
    return ((e[1] | e[3] | e[5] | e[7]) == 0);
}
__device__ __forceinline__ int load_src(const int* e, int i, int E, bool is64) {
    return e[is64 ? (long)2 * i : (long)i];
}
__device__ __forceinline__ int load_dst(const int* e, int i, int E, bool is64) {
    return e[is64 ? (long)2 * (E + i) : (long)(E + i)];
}
// acc_lo += f32(lo16(h)); acc_hi += f32(hi16(h)) -- one VALU op each,
// bitwise identical to v_cvt_f32_f16 + v_add_f32 (x*1.0 exact).
__device__ __forceinline__ void fmix2(float& alo, float& ahi, unsigned h) {
    asm("v_fma_mix_f32 %0, %2, 1.0, %0 op_sel_hi:[1,0,0]\n\t"
        "v_fma_mix_f32 %1, %2, 1.0, %1 op_sel:[1,0,0] op_sel_hi:[1,0,0]"
        : "+v"(alo), "+v"(ahi) : "v"(h));
}

// ---- pass A: chunk reservation (unchanged from round-0) ----
__global__ __launch_bounds__(256) void passA(const int* __restrict__ e,
                                             int* __restrict__ bcnt,
                                             int* __restrict__ ebuf, int E, int B) {
    __shared__ int lcnt[MAXB], lbase[MAXB];
    bool is64 = detect64(e);
    bool vec = ((E & 3) == 0);
    int base = blockIdx.x * CHUNK;
    for (int t = threadIdx.x; t < B; t += 256) lcnt[t] = 0;
    __syncthreads();
    int pk[16], bk[16], rk[16];
#pragma unroll
    for (int g = 0; g < 4; ++g) {
        int i = base + (((g << 8) + (int)threadIdx.x) << 2);
        int r = g * 4;
        if (vec && i + 3 < E) {
            int4 s4, d4;
            if (is64) {
                const int4* p = (const int4*)(e + (size_t)2 * i);
                int4 a = p[0], bb = p[1];
                s4 = make_int4(a.x, a.z, bb.x, bb.z);
                const int4* q = (const int4*)(e + (size_t)2 * E + (size_t)2 * i);
                int4 c = q[0], dd = q[1];
                d4 = make_int4(c.x, c.z, dd.x, dd.z);
            } else {
                s4 = *(const int4*)(e + i);
                d4 = *(const int4*)(e + E + i);
            }
            int ss[4] = {s4.x, s4.y, s4.z, s4.w};
            int dv[4] = {d4.x, d4.y, d4.z, d4.w};
#pragma unroll
            for (int u = 0; u < 4; ++u) {
                pk[r + u] = ss[u] | ((dv[u] & (GSZ - 1)) << 17);
                bk[r + u] = dv[u] >> GSH;
                rk[r + u] = atomicAdd(&lcnt[bk[r + u]], 1);
            }
        } else {
#pragma unroll
            for (int u = 0; u < 4; ++u) {
                int ii = i + u;
                if (ii < E) {
                    int s = load_src(e, ii, E, is64);
                    int d = load_dst(e, ii, E, is64);
                    pk[r + u] = s | ((d & (GSZ - 1)) << 17);
                    bk[r + u] = d >> GSH;
                    rk[r + u] = atomicAdd(&lcnt[bk[r + u]], 1);
                } else {
                    bk[r + u] = -1;
                }
            }
        }
    }
    __syncthreads();
    for (int t = threadIdx.x; t < B; t += 256) {
        int c = lcnt[t];
        lbase[t] = c ? atomicAdd(&bcnt[t], c) : 0;
    }
    __syncthreads();
#pragma unroll
    for (int r = 0; r < 16; ++r) {
        if (bk[r] >= 0) {
            int pos = lbase[bk[r]] + rk[r];
            if (pos < CAP) ebuf[((size_t)bk[r] << CAPSH) + pos] = pk[r];
        }
    }
}

// ---- pass B: per-bucket sort -> deg/rowStart/dinv/srcSorted (y16 prep
// removed: the dense transform moved to gemm1) ----
__global__ __launch_bounds__(256) void passB(const int* __restrict__ ebuf,
                                             const int* __restrict__ bcnt,
                                             int* __restrict__ rowStart,
                                             int* __restrict__ deg,
                                             float* __restrict__ dinv,
                                             int* __restrict__ srcSorted, int N) {
    __shared__ int cnt[GSZ], inc[GSZ], exo[GSZ];
    int b = blockIdx.x, t = threadIdx.x;
    int m = min(bcnt[b], CAP);
    const int* eb = ebuf + ((size_t)b << CAPSH);
    if (t < GSZ) cnt[t] = 0;
    __syncthreads();
    int gk[16], sk[16], rk[16];
    int iters = (m + 255) >> 8;   // <= 16
    for (int it = 0; it < iters; ++it) {
        int i = t + (it << 8);
        if (i < m) {
            int pkv = eb[i];
            gk[it] = pkv >> 17;
            sk[it] = pkv & 0x1FFFF;
            rk[it] = atomicAdd(&cnt[gk[it]], 1);
        } else {
            gk[it] = -1;
        }
    }
    __syncthreads();
    int myc = (t < GSZ) ? cnt[t] : 0;
    if (t < GSZ) inc[t] = myc;
    __syncthreads();
    for (int o = 1; o < GSZ; o <<= 1) {
        int v = (t < GSZ && t >= o) ? inc[t - o] : 0;
        __syncthreads();
        if (t < GSZ) inc[t] += v;
        __syncthreads();
    }
    if (t < GSZ) {
        int ex = inc[t] - myc;
        exo[t] = ex;
        int node = (b << GSH) + t;
        if (node < N) {
            rowStart[node] = (b << CAPSH) + ex;
            deg[node] = myc;
            dinv[node] = rsqrtf((float)myc + 1.0f);
        }
    }
    __syncthreads();
    int s0b = b << CAPSH;
    for (int it = 0; it < iters; ++it) {
        if (gk[it] >= 0)
            srcSorted[s0b + exo[gk[it]] + rk[it]] = sk[it];
    }
}

// ---- gemm1: H[n][j] = fp16(dinv[n] * sum_k x[n][k] * W1[k][j]).
// One wave = 64 j-lanes; W1 column held in 48 VGPRs; x rows read via
// wave-uniform pointers (scalar loads); 2-node software pipeline. ----
__global__ __launch_bounds__(256) void gemm1(const float* __restrict__ x,
                                             const float* __restrict__ W1,
                                             const float* __restrict__ dinv,
                                             __half* __restrict__ H, int N) {
    const int lane = threadIdx.x & 63;
    const int warp = __builtin_amdgcn_readfirstlane((int)(threadIdx.x >> 6));
    const int nb = (blockIdx.x * 4 + warp) * NPW;
    float w[F_IN];
#pragma unroll
    for (int k = 0; k < F_IN; ++k) w[k] = W1[k * F_HID + lane];
    for (int u = 0; u < NPW; u += 2) {
        int na = nb + u, nb2 = nb + u + 1;
        int nac = min(na, N - 1), nbc = min(nb2, N - 1);
        const float* xra = x + (size_t)nac * F_IN;
        const float* xrb = x + (size_t)nbc * F_IN;
        float ha = 0.0f, hb = 0.0f;
#pragma unroll
        for (int k = 0; k < F_IN; ++k) {
            ha = fmaf(xra[k], w[k], ha);
            hb = fmaf(xrb[k], w[k], hb);
        }
        if (na < N)
            H[(size_t)na * F_HID + lane] = __float2half(dinv[nac] * ha);
        if (nb2 < N)
            H[(size_t)nb2 * F_HID + lane] = __float2half(dinv[nbc] * hb);
    }
}

// ---- agg1: 4 nodes/wave gather-sum of H rows (128 B, row N = zeros),
// 24 loads batched in flight; tiny relu+W2 epilogue (no per-node GEMM). ----
__global__ __launch_bounds__(256) void agg1(const __half* __restrict__ H,
                                            const float* __restrict__ b1,
                                            const float* __restrict__ W2,
                                            const float* __restrict__ dinv,
                                            const int* __restrict__ rowStart,
                                            const int* __restrict__ deg,
                                            const int* __restrict__ srcSorted,
                                            float* __restrict__ g2, int N) {
    const int lane = threadIdx.x & 63;
    const int sub = lane >> 5;
    const int fl = lane & 31;
    const int base = blockIdx.x * 16 + (threadIdx.x >> 6) * 4;
    const char* hb = (const char*)H;
    const unsigned fb = (unsigned)fl << 2;

    int n0 = base, n1 = base + 1, n2 = base + 2, n3 = base + 3;
    int dn0 = (n0 < N) ? deg[n0] : -1;
    int dn1 = (n1 < N) ? deg[n1] : -1;
    int dn2_ = (n2 < N) ? deg[n2] : -1;
    int dn3 = (n3 < N) ? deg[n3] : -1;
    int rs0 = (n0 < N) ? rowStart[n0] : 0;
    int rs1 = (n1 < N) ? rowStart[n1] : 0;
    int rs2 = (n2 < N) ? rowStart[n2] : 0;
    int rs3 = (n3 < N) ? rowStart[n3] : 0;

    // slot map per lane: [0,dn)=edges, dn=self, rest=zero row N
    int idx0 = N, idx1 = N, idx2 = N, idx3 = N;
    if (lane < dn0) idx0 = srcSorted[rs0 + lane]; else if (lane == dn0) idx0 = n0;
    if (lane < dn1) idx1 = srcSorted[rs1 + lane]; else if (lane == dn1) idx1 = n1;
    if (lane < dn2_) idx2 = srcSorted[rs2 + lane]; else if (lane == dn2_) idx2 = n2;
    if (lane < dn3) idx3 = srcSorted[rs3 + lane]; else if (lane == dn3) idx3 = n3;

    float ax0 = 0, ay0 = 0, ax1 = 0, ay1 = 0;
    float ax2 = 0, ay2 = 0, ax3 = 0, ay3 = 0;

    // 6-step batch = 24 independent gathers fully in flight before consume
    auto batch6 = [&](int p0) {
        unsigned o[6][4], v[6][4];
#pragma unroll
        for (int p = 0; p < 6; ++p) {
            int sA = 2 * (p0 + p) + sub;
            o[p][0] = ((unsigned)__shfl(idx0, sA, 64) << 7) + fb;
            o[p][1] = ((unsigned)__shfl(idx1, sA, 64) << 7) + fb;
            o[p][2] = ((unsigned)__shfl(idx2, sA, 64) << 7) + fb;
            o[p][3] = ((unsigned)__shfl(idx3, sA, 64) << 7) + fb;
        }
#pragma unroll
        for (int p = 0; p < 6; ++p) {
            v[p][0] = *(const unsigned*)(hb + o[p][0]);
            v[p][1] = *(const unsigned*)(hb + o[p][1]);
            v[p][2] = *(const unsigned*)(hb + o[p][2]);
            v[p][3] = *(const unsigned*)(hb + o[p][3]);
        }
#pragma unroll
        for (int p = 0; p < 6; ++p) {
            fmix2(ax0, ay0, v[p][0]);
            fmix2(ax1, ay1, v[p][1]);
            fmix2(ax2, ay2, v[p][2]);
            fmix2(ax3, ay3, v[p][3]);
        }
    };
    batch6(0);   // slots 0..11
    batch6(6);   // slots 12..23

    int maxD = max(max(dn0, dn1), max(dn2_, dn3));
    int maxSlot = maxD + 1;
    for (int p = 12; p < 32 && 2 * p < maxSlot; ++p) {   // uncommon (deg>=24)
        int sA = 2 * p + sub;
        unsigned o0 = ((unsigned)__shfl(idx0, sA, 64) << 7) + fb;
        unsigned o1 = ((unsigned)__shfl(idx1, sA, 64) << 7) + fb;
        unsigned o2 = ((unsigned)__shfl(idx2, sA, 64) << 7) + fb;
        unsigned o3 = ((unsigned)__shfl(idx3, sA, 64) << 7) + fb;
        unsigned v0 = *(const unsigned*)(hb + o0);
        unsigned v1 = *(const unsigned*)(hb + o1);
        unsigned v2 = *(const unsigned*)(hb + o2);
        unsigned v3 = *(const unsigned*)(hb + o3);
        fmix2(ax0, ay0, v0);
        fmix2(ax1, ay1, v1);
        fmix2(ax2, ay2, v2);
        fmix2(ax3, ay3, v3);
    }
    if (maxSlot > 64) {  // astronomically rare
        const __half2* hp = (const __half2*)H;
        for (int s = 64; s < maxSlot; ++s) {
            if (sub == 0) {
                if (s <= dn0) { float2 f = __half22float2(hp[((long)((s < dn0) ? srcSorted[rs0 + s] : n0) << 5) + fl]); ax0 += f.x; ay0 += f.y; }
                if (s <= dn1) { float2 f = __half22float2(hp[((long)((s < dn1) ? srcSorted[rs1 + s] : n1) << 5) + fl]); ax1 += f.x; ay1 += f.y; }
                if (s <= dn2_) { float2 f = __half22float2(hp[((long)((s < dn2_) ? srcSorted[rs2 + s] : n2) << 5) + fl]); ax2 += f.x; ay2 += f.y; }
                if (s <= dn3) { float2 f = __half22float2(hp[((long)((s < dn3) ? srcSorted[rs3 + s] : n3) << 5) + fl]); ax3 += f.x; ay3 += f.y; }
            }
        }
    }

    // combine half-waves: lane fl then holds a[2*fl], a[2*fl+1] (both halves)
    ax0 += __shfl(ax0, lane ^ 32, 64); ay0 += __shfl(ay0, lane ^ 32, 64);
    ax1 += __shfl(ax1, lane ^ 32, 64); ay1 += __shfl(ay1, lane ^ 32, 64);
    ax2 += __shfl(ax2, lane ^ 32, 64); ay2 += __shfl(ay2, lane ^ 32, 64);
    ax3 += __shfl(ax3, lane ^ 32, 64); ay3 += __shfl(ay3, lane ^ 32, 64);
    float di0 = (n0 < N) ? dinv[n0] : 0.0f;
    float di1 = (n1 < N) ? dinv[n1] : 0.0f;
    float di2 = (n2 < N) ? dinv[n2] : 0.0f;
    float di3 = (n3 < N) ? dinv[n3] : 0.0f;

    // epilogue: h = relu(di*a + b1); t = h . W2 (2 cols); reduce 32 lanes
    float2 b1v = *(const float2*)(b1 + 2 * fl);
    float4 w2q = *(const float4*)(W2 + 4 * fl);   // [2fl][0],[2fl][1],[2fl+1][0],[2fl+1][1]
    float hA, hB;
    hA = fmaxf(fmaf(di0, ax0, b1v.x), 0.0f); hB = fmaxf(fmaf(di0, ay0, b1v.y), 0.0f);
    float t00 = hA * w2q.x + hB * w2q.z, t01 = hA * w2q.y + hB * w2q.w;
    hA = fmaxf(fmaf(di1, ax1, b1v.x), 0.0f); hB = fmaxf(fmaf(di1, ay1, b1v.y), 0.0f);
    float t10 = hA * w2q.x + hB * w2q.z, t11 = hA * w2q.y + hB * w2q.w;
    hA = fmaxf(fmaf(di2, ax2, b1v.x), 0.0f); hB = fmaxf(fmaf(di2, ay2, b1v.y), 0.0f);
    float t20 = hA * w2q.x + hB * w2q.z, t21 = hA * w2q.y + hB * w2q.w;
    hA = fmaxf(fmaf(di3, ax3, b1v.x), 0.0f); hB = fmaxf(fmaf(di3, ay3, b1v.y), 0.0f);
    float t30 = hA * w2q.x + hB * w2q.z, t31 = hA * w2q.y + hB * w2q.w;
#pragma unroll
    for (int m = 1; m <= 16; m <<= 1) {
        t00 += __shfl_xor(t00, m, 64); t01 += __shfl_xor(t01, m, 64);
        t10 += __shfl_xor(t10, m, 64); t11 += __shfl_xor(t11, m, 64);
        t20 += __shfl_xor(t20, m, 64); t21 += __shfl_xor(t21, m, 64);
        t30 += __shfl_xor(t30, m, 64); t31 += __shfl_xor(t31, m, 64);
    }
    if (lane == 0) {
        float2* g2v = (float2*)g2;
        if (n0 < N) g2v[n0] = make_float2(di0 * t00, di0 * t01);
        if (n1 < N) g2v[n1] = make_float2(di1 * t10, di1 * t11);
        if (n2 < N) g2v[n2] = make_float2(di2 * t20, di2 * t21);
        if (n3 < N) g2v[n3] = make_float2(di3 * t30, di3 * t31);
    }
}

// ---- layer-2 aggregation: 16 lanes per node, 32-bit offsets ----
__global__ __launch_bounds__(256) void agg2(const int* __restrict__ rowStart,
                                            const int* __restrict__ deg,
                                            const int* __restrict__ srcSorted,
                                            const float* __restrict__ g2,
                                            const float* __restrict__ dinv,
                                            const float* __restrict__ b2,
                                            float* __restrict__ out, int N) {
    int gid = blockIdx.x * 256 + threadIdx.x;
    int node = gid >> 4, l16 = gid & 15;
    if (node >= N) return;
    const char* gb = (const char*)g2;
    int rs = rowStart[node], dn = deg[node];
    float a0 = 0.0f, a1 = 0.0f;
    for (int j = l16; j < dn; j += 16) {
        unsigned o = (unsigned)srcSorted[rs + j] << 3;
        float2 v = *(const float2*)(gb + o);
        a0 += v.x;
        a1 += v.y;
    }
#pragma unroll
    for (int m = 1; m < 16; m <<= 1) {
        a0 += __shfl_xor(a0, m, 64);
        a1 += __shfl_xor(a1, m, 64);
    }
    if (l16 == 0) {
        float2 self = *(const float2*)(gb + ((unsigned)node << 3));
        float di = dinv[node];
        out[2 * node + 0] = di * (a0 + self.x) + b2[0];
        out[2 * node + 1] = di * (a1 + self.y) + b2[1];
    }
}

extern "C" void kernel_launch(void* const* d_in, const int* in_sizes, int n_in,
                              void* d_out, int out_size, void* d_ws, size_t ws_size,
                              hipStream_t stream) {
    const float* x  = (const float*)d_in[0];
    const int* eidx = (const int*)d_in[1];
    const float* W1 = (const float*)d_in[2];
    const float* b1 = (const float*)d_in[3];
    const float* W2 = (const float*)d_in[4];
    const float* b2 = (const float*)d_in[5];
    float* out = (float*)d_out;

    int N = in_sizes[0] / F_IN;   // 100000
    int E = in_sizes[1] / 2;      // 1600000
    int B = (N + GSZ - 1) >> GSH; // 782 buckets (<= MAXB)

    // layout: H rows 0..N (row N = zero row), then bcnt — adjacent so one
    // memset clears both (row N is 128 B; bcnt is MAXB*4 B).
    char* ws = (char*)d_ws;
    __half* H         = (__half*)ws;   ws += (size_t)(N + 1) * F_HID * 2;
    int*    bcnt      = (int*)ws;      ws += MAXB * 4;
    int*    deg       = (int*)ws;      ws += (size_t)N * 4;
    int*    rowStart  = (int*)ws;      ws += (size_t)N * 4;
    float*  dinv      = (float*)ws;    ws += (size_t)N * 4;
    float*  g2        = (float*)ws;    ws += (size_t)N * 2 * 4;
    ws = (char*)(((size_t)ws + 255) & ~(size_t)255);
    int*    ebuf      = (int*)ws;      ws += (size_t)MAXB * CAP * 4;
    int*    srcSorted = (int*)ws;      ws += (size_t)MAXB * CAP * 4;

    hipMemsetAsync(H + (size_t)N * F_HID, 0, 128 + MAXB * 4, stream);

    passA<<<(E + CHUNK - 1) / CHUNK, 256, 0, stream>>>(eidx, bcnt, ebuf, E, B);
    passB<<<B, 256, 0, stream>>>(ebuf, bcnt, rowStart, deg, dinv, srcSorted, N);
    gemm1<<<(N + 4 * NPW - 1) / (4 * NPW), 256, 0, stream>>>(x, W1, dinv, H, N);
    agg1<<<(N + 15) / 16, 256, 0, stream>>>(H, b1, W2, dinv, rowStart, deg,
                                            srcSorted, g2, N);
    agg2<<<(N * 16 + 255) / 256, 256, 0, stream>>>(rowStart, deg, srcSorted, g2,
                                                   dinv, b2, out, N);
}